// Round 2
// baseline (792.211 us; speedup 1.0000x reference)
//
#include <hip/hip_runtime.h>
#include <math.h>

#define N_NODES 100000
#define N_EDGES 1600000

// ---------------- CSR build ----------------

__global__ void count_deg_kernel(const int* __restrict__ dst, int* __restrict__ counts) {
    int e = blockIdx.x * 256 + threadIdx.x;
    if (e < N_EDGES) atomicAdd(&counts[dst[e]], 1);
}

__global__ void compute_deg_kernel(const int* __restrict__ counts,
                                   float* __restrict__ dis) {
    int i = blockIdx.x * 256 + threadIdx.x;
    if (i < N_NODES) {
        float deg = (float)(counts[i] + 1);   // self-loop
        dis[i] = rsqrtf(deg);
    }
}

// Exclusive prefix scan over counts -> rowstart. 3 phases.
__global__ void scanA_kernel(const int* __restrict__ counts, int* __restrict__ rowstart,
                             int* __restrict__ bsums) {
    __shared__ int s[256];
    int i = blockIdx.x * 256 + threadIdx.x;
    int v = (i < N_NODES) ? counts[i] : 0;
    s[threadIdx.x] = v;
    __syncthreads();
    for (int off = 1; off < 256; off <<= 1) {
        int t = 0;
        if (threadIdx.x >= off) t = s[threadIdx.x - off];
        __syncthreads();
        s[threadIdx.x] += t;
        __syncthreads();
    }
    if (i < N_NODES) rowstart[i] = s[threadIdx.x] - v;   // exclusive within block
    if (threadIdx.x == 255) bsums[blockIdx.x] = s[255];
}

__global__ void scanB_kernel(int* __restrict__ bsums, int nb) {
    __shared__ int s[512];
    int t = threadIdx.x;
    int v = (t < nb) ? bsums[t] : 0;
    s[t] = v;
    __syncthreads();
    for (int off = 1; off < 512; off <<= 1) {
        int u = 0;
        if (t >= off) u = s[t - off];
        __syncthreads();
        s[t] += u;
        __syncthreads();
    }
    if (t < nb) bsums[t] = s[t] - v;   // exclusive block offsets
}

__global__ void scanC_kernel(int* __restrict__ rowstart, const int* __restrict__ bsums) {
    int i = blockIdx.x * 256 + threadIdx.x;
    if (i < N_NODES) rowstart[i] += bsums[blockIdx.x];
}

__global__ void csr_fill_kernel(const int* __restrict__ src, const int* __restrict__ dst,
                                const int* __restrict__ rowstart, int* __restrict__ cursor,
                                int* __restrict__ csr_src) {
    int e = blockIdx.x * 256 + threadIdx.x;
    if (e < N_EDGES) {
        int d = dst[e];
        int pos = rowstart[d] + atomicAdd(&cursor[d], 1);
        csr_src[pos] = src[e];
    }
}

// ---------------- GEMM: Y[N,128] = (X[N,128] @ W[128,128]) * scale[row] ----------------
// 64x128 tile, BK=16, 256 threads, 4x8 micro-tile. A stored transposed in LDS.

__global__ __launch_bounds__(256) void gemm128_kernel(const float* __restrict__ X,
                                                      const float* __restrict__ W,
                                                      const float* __restrict__ scale,
                                                      float* __restrict__ Y, int nrows) {
    __shared__ float As[16][68];   // [k][row], pad 68 keeps b128 reads clean
    __shared__ float Bs[16][128];
    int tid = threadIdx.x;
    int tx = tid & 15;    // col group: cols tx*8 .. tx*8+7
    int ty = tid >> 4;    // row group: rows ty*4 .. ty*4+3
    int rowBase = blockIdx.x * 64;

    float acc[4][8];
#pragma unroll
    for (int i = 0; i < 4; i++)
#pragma unroll
        for (int j = 0; j < 8; j++) acc[i][j] = 0.f;

    // A-load mapping: each thread one float4: row r = tid>>2 (0..63), c4 = tid&3
    int a_r  = tid >> 2;
    int a_c4 = tid & 3;
    // B-load mapping: each thread two float4s: c4b = tid&31, kb0 = tid>>5 (0..7)
    int b_c4 = tid & 31;
    int b_k0 = tid >> 5;

    for (int kb = 0; kb < 128; kb += 16) {
        {
            int grow = rowBase + a_r;
            float4 v = make_float4(0.f, 0.f, 0.f, 0.f);
            if (grow < nrows) v = *(const float4*)&X[grow * 128 + kb + a_c4 * 4];
            As[a_c4 * 4 + 0][a_r] = v.x;
            As[a_c4 * 4 + 1][a_r] = v.y;
            As[a_c4 * 4 + 2][a_r] = v.z;
            As[a_c4 * 4 + 3][a_r] = v.w;
        }
        {
#pragma unroll
            for (int kk2 = 0; kk2 < 2; kk2++) {
                int k = b_k0 + kk2 * 8;
                float4 v = *(const float4*)&W[(kb + k) * 128 + b_c4 * 4];
                *(float4*)&Bs[k][b_c4 * 4] = v;
            }
        }
        __syncthreads();
#pragma unroll
        for (int kk = 0; kk < 16; kk++) {
            float4 a4 = *(const float4*)&As[kk][ty * 4];
            float4 b4a = *(const float4*)&Bs[kk][tx * 8];
            float4 b4b = *(const float4*)&Bs[kk][tx * 8 + 4];
            float a[4] = {a4.x, a4.y, a4.z, a4.w};
            float b[8] = {b4a.x, b4a.y, b4a.z, b4a.w, b4b.x, b4b.y, b4b.z, b4b.w};
#pragma unroll
            for (int i = 0; i < 4; i++)
#pragma unroll
                for (int j = 0; j < 8; j++) acc[i][j] += a[i] * b[j];
        }
        __syncthreads();
    }
#pragma unroll
    for (int i = 0; i < 4; i++) {
        int grow = rowBase + ty * 4 + i;
        if (grow < nrows) {
            float s = scale ? scale[grow] : 1.0f;
            float4 o0 = make_float4(acc[i][0] * s, acc[i][1] * s, acc[i][2] * s, acc[i][3] * s);
            float4 o1 = make_float4(acc[i][4] * s, acc[i][5] * s, acc[i][6] * s, acc[i][7] * s);
            *(float4*)&Y[grow * 128 + tx * 8]     = o0;
            *(float4*)&Y[grow * 128 + tx * 8 + 4] = o1;
        }
    }
}

// ---------------- Aggregation ----------------
// Hs[i] = h[i]*dis[i] (pre-scaled by GEMM epilogue).
// out[i] = relu( b + dis[i] * (Hs[i] + sum_{e:dst=i} Hs[src]) )
// One wave per node; lane owns 2 channels -> each gather is one 512B coalesced row.

__global__ __launch_bounds__(256) void aggregate_kernel(const float* __restrict__ Hs,
                                                        const float* __restrict__ dis,
                                                        const int* __restrict__ rowstart,
                                                        const int* __restrict__ counts,
                                                        const int* __restrict__ csr_src,
                                                        const float* __restrict__ bias,
                                                        float* __restrict__ Out) {
    int node = blockIdx.x * 4 + (threadIdx.x >> 6);
    node = __builtin_amdgcn_readfirstlane(node);   // wave-uniform -> scalar loads
    int lane = threadIdx.x & 63;
    if (node >= N_NODES) return;
    int c0 = lane * 2;

    float2 own = *(const float2*)&Hs[node * 128 + c0];
    float accx = own.x, accy = own.y;

    int start = rowstart[node];
    int cnt   = counts[node];

    int j = start;
    int end = start + cnt;
    for (; j + 3 < end; j += 4) {
        int s0 = csr_src[j];
        int s1 = csr_src[j + 1];
        int s2 = csr_src[j + 2];
        int s3 = csr_src[j + 3];
        float2 v0 = *(const float2*)&Hs[s0 * 128 + c0];
        float2 v1 = *(const float2*)&Hs[s1 * 128 + c0];
        float2 v2 = *(const float2*)&Hs[s2 * 128 + c0];
        float2 v3 = *(const float2*)&Hs[s3 * 128 + c0];
        accx += v0.x + v1.x + v2.x + v3.x;
        accy += v0.y + v1.y + v2.y + v3.y;
    }
    for (; j < end; j++) {
        int s0 = csr_src[j];
        float2 v0 = *(const float2*)&Hs[s0 * 128 + c0];
        accx += v0.x;
        accy += v0.y;
    }

    float dsi = dis[node];
    float2 bb = *(const float2*)&bias[c0];
    float2 r;
    r.x = fmaxf(accx * dsi + bb.x, 0.f);
    r.y = fmaxf(accy * dsi + bb.y, 0.f);
    *(float2*)&Out[node * 128 + c0] = r;
}

// ---------------- Final: out = sigmoid(H @ Wr + br)*0.8 + 0.1 ----------------

__global__ __launch_bounds__(256) void final_kernel(const float* __restrict__ H,
                                                    const float* __restrict__ Wr,
                                                    const float* __restrict__ br,
                                                    float* __restrict__ out) {
    __shared__ float hs[16][132];
    __shared__ float ws[128][16];
    int tid = threadIdx.x;
    int rowBase = blockIdx.x * 16;
    {
        int k  = tid & 127;
        int r0 = tid >> 7;   // 0..1
#pragma unroll
        for (int rr = 0; rr < 8; rr++) {
            int r = r0 + rr * 2;
            int grow = rowBase + r;
            hs[r][k] = (grow < N_NODES) ? H[grow * 128 + k] : 0.f;
        }
        // Wr: 128*16 = 2048 floats, 256 threads x 8
#pragma unroll
        for (int q = 0; q < 8; q++) {
            int idx = q * 256 + tid;
            ws[idx >> 4][idx & 15] = Wr[idx];
        }
    }
    __syncthreads();
    int row = tid >> 4;
    int c   = tid & 15;
    float acc = br[c];
#pragma unroll
    for (int k = 0; k < 128; k++)
        acc += hs[row][k] * ws[k][c];
    int grow = rowBase + row;
    if (grow < N_NODES) {
        float s = 1.f / (1.f + expf(-acc));
        out[grow * 16 + c] = 0.8f * s + 0.1f;
    }
}

// ---------------- Launch ----------------

extern "C" void kernel_launch(void* const* d_in, const int* in_sizes, int n_in,
                              void* d_out, int out_size, void* d_ws, size_t ws_size,
                              hipStream_t stream) {
    const float* x  = (const float*)d_in[0];
    const int*   ei = (const int*)d_in[1];
    const int*   src = ei;
    const int*   dst = ei + N_EDGES;
    const float* W0 = (const float*)d_in[2];
    const float* b0 = (const float*)d_in[3];
    const float* W1 = (const float*)d_in[4];
    const float* b1 = (const float*)d_in[5];
    const float* W2 = (const float*)d_in[6];
    const float* b2 = (const float*)d_in[7];
    const float* Wr = (const float*)d_in[8];
    const float* br = (const float*)d_in[9];
    float* out = (float*)d_out;

    char* ws = (char*)d_ws;
    size_t off = 0;
    auto take = [&](size_t bytes) {
        char* p = ws + off;
        off += (bytes + 255) & ~(size_t)255;
        return p;
    };
    float* hA      = (float*)take((size_t)N_NODES * 128 * 4);
    float* hB      = (float*)take((size_t)N_NODES * 128 * 4);
    int*   counts  = (int*)take((size_t)N_NODES * 4);
    int*   rowstart= (int*)take((size_t)N_NODES * 4);
    int*   cursor  = (int*)take((size_t)N_NODES * 4);
    float* dis     = (float*)take((size_t)N_NODES * 4);
    int*   csr_src = (int*)take((size_t)N_EDGES * 4);
    int*   bsums   = (int*)take(1024 * 4);
    (void)ws_size; (void)in_sizes; (void)n_in; (void)out_size;

    hipMemsetAsync(counts, 0, (size_t)N_NODES * 4, stream);
    hipMemsetAsync(cursor, 0, (size_t)N_NODES * 4, stream);

    int nbE = (N_EDGES + 255) / 256;
    int nbN = (N_NODES + 255) / 256;   // 391

    count_deg_kernel<<<nbE, 256, 0, stream>>>(dst, counts);
    compute_deg_kernel<<<nbN, 256, 0, stream>>>(counts, dis);
    scanA_kernel<<<nbN, 256, 0, stream>>>(counts, rowstart, bsums);
    scanB_kernel<<<1, 512, 0, stream>>>(bsums, nbN);
    scanC_kernel<<<nbN, 256, 0, stream>>>(rowstart, bsums);
    csr_fill_kernel<<<nbE, 256, 0, stream>>>(src, dst, rowstart, cursor, csr_src);

    const float* Wl[3] = {W0, W1, W2};
    const float* bl[3] = {b0, b1, b2};
    const float* hin = x;
    for (int l = 0; l < 3; l++) {
        // hB = (hin @ Wl) * dis  (pre-scaled by deg_inv_sqrt)
        gemm128_kernel<<<(N_NODES + 63) / 64, 256, 0, stream>>>(hin, Wl[l], dis, hB, N_NODES);
        aggregate_kernel<<<N_NODES / 4, 256, 0, stream>>>(hB, dis, rowstart, counts,
                                                          csr_src, bl[l], hA);
        hin = hA;
    }
    final_kernel<<<N_NODES / 16, 256, 0, stream>>>(hA, Wr, br, out);
}